// Round 1
// baseline (16263.870 us; speedup 1.0000x reference)
//
#include <hip/hip_runtime.h>
#include <stdint.h>

typedef __attribute__((ext_vector_type(8))) short short8;
typedef __attribute__((ext_vector_type(4))) float floatx4;

#define S_LEN 512
#define BATCH 64
#define HID   1024
#define GATES 4096
#define EMB   1024
#define M_ROWS 32768  // S*B

__device__ __forceinline__ short f2bf(float f) {
  unsigned u = __float_as_uint(f);
  unsigned r = (u + 0x7fffu + ((u >> 16) & 1u)) >> 16;
  return (short)r;
}
__device__ __forceinline__ float bf2f(short v) {
  return __uint_as_float(((unsigned)(unsigned short)v) << 16);
}
__device__ __forceinline__ void ld_lds16(const void* g, void* l) {
  __builtin_amdgcn_global_load_lds((const __attribute__((address_space(1))) void*)g,
                                   (__attribute__((address_space(3))) void*)l, 16, 0, 0);
}

// ---------------- embedding gather: X[s*64+b][k] = bf16(table[tok[b][s]][k])
__global__ __launch_bounds__(256) void k_gather(const int* __restrict__ tok,
                                                const float* __restrict__ table,
                                                short* __restrict__ X) {
  int r = blockIdx.x;
  int b = r & 63, s = r >> 6;
  int t = tok[b * S_LEN + s];
  const float* src = table + (size_t)t * EMB;
  short* dst = X + (size_t)r * EMB;
  for (int k = threadIdx.x; k < EMB; k += 256) dst[k] = f2bf(src[k]);
}

// ---------------- transpose W (1024 x 4096 fp32) -> WT (4096 x 1024 bf16)
__global__ __launch_bounds__(256) void k_transpose(const float* __restrict__ W,
                                                   short* __restrict__ WT) {
  __shared__ short tile[32][33];
  int k0 = blockIdx.x * 32, n0 = blockIdx.y * 32;
  int tx = threadIdx.x & 31, ty = threadIdx.x >> 5;
#pragma unroll
  for (int i = 0; i < 32; i += 8)
    tile[ty + i][tx] = f2bf(W[(size_t)(k0 + ty + i) * GATES + n0 + tx]);
  __syncthreads();
#pragma unroll
  for (int i = 0; i < 32; i += 8)
    WT[(size_t)(n0 + ty + i) * HID + k0 + tx] = tile[tx][ty + i];
}

// ---------------- zero init (h, c state)
__global__ __launch_bounds__(256) void k_zero(uint32_t* p, int n) {
  int i = blockIdx.x * 256 + threadIdx.x;
  if (i < n) p[i] = 0u;
}

// ---------------- input-projection GEMM: Gin = X @ Wx + b   (bf16 out)
// M=32768, N=4096, K=1024. 128x128 tile, BK=32, global_load_lds staging.
__global__ __launch_bounds__(256) void k_gemm_in(const short* __restrict__ X,
                                                 const short* __restrict__ WT_f,
                                                 const short* __restrict__ WT_b,
                                                 const float* __restrict__ bias_f,
                                                 const float* __restrict__ bias_b,
                                                 short* __restrict__ Gin_f,
                                                 short* __restrict__ Gin_b) {
  const short* WT   = blockIdx.z ? WT_b : WT_f;
  const float* bias = blockIdx.z ? bias_b : bias_f;
  short* Gin        = blockIdx.z ? Gin_b : Gin_f;
  __shared__ __align__(16) short sA[128 * 32];
  __shared__ __align__(16) short sB[128 * 32];
  int tid = threadIdx.x;
  int lane = tid & 63, wave = tid >> 6;
  int n0 = blockIdx.x * 128, m0 = blockIdx.y * 128;  // x = N tiles for L2 locality
  int wm = (wave & 1) * 64, wn = (wave >> 1) * 64;
  int lm = lane & 15, lk = (lane >> 4) * 8;
  floatx4 acc[4][4];
  for (int i = 0; i < 4; i++)
    for (int j = 0; j < 4; j++)
      for (int r = 0; r < 4; r++) acc[i][j][r] = 0.f;

  for (int kt = 0; kt < HID; kt += 32) {
    __syncthreads();
#pragma unroll
    for (int i = 0; i < 2; i++) {
      int c = tid + i * 256;
      int row = c >> 2, k8 = (c & 3) * 8;
      ld_lds16(X + (size_t)(m0 + row) * HID + kt + k8, sA + c * 8);
    }
#pragma unroll
    for (int i = 0; i < 2; i++) {
      int c = tid + i * 256;
      int row = c >> 2, k8 = (c & 3) * 8;
      ld_lds16(WT + (size_t)(n0 + row) * HID + kt + k8, sB + c * 8);
    }
    __syncthreads();
    short8 af[4], bf4[4];
#pragma unroll
    for (int mi = 0; mi < 4; mi++) af[mi] = *(const short8*)&sA[(wm + mi * 16 + lm) * 32 + lk];
#pragma unroll
    for (int ni = 0; ni < 4; ni++) bf4[ni] = *(const short8*)&sB[(wn + ni * 16 + lm) * 32 + lk];
#pragma unroll
    for (int mi = 0; mi < 4; mi++)
#pragma unroll
      for (int ni = 0; ni < 4; ni++)
        acc[mi][ni] = __builtin_amdgcn_mfma_f32_16x16x32_bf16(af[mi], bf4[ni], acc[mi][ni], 0, 0, 0);
  }
  int lr = lane >> 4;
#pragma unroll
  for (int mi = 0; mi < 4; mi++)
    for (int ni = 0; ni < 4; ni++)
      for (int r = 0; r < 4; r++) {
        int m = m0 + wm + mi * 16 + lr * 4 + r;
        int n = n0 + wn + ni * 16 + lm;
        Gin[(size_t)m * GATES + n] = f2bf(acc[mi][ni][r] + bias[n]);
      }
}

// ---------------- one LSTM time step, both directions
// grid = 128 WGs (0..63 fwd, 64..127 bwd), 256 thr. WG owns 16 h-cols, wave g = gate g.
__global__ __launch_bounds__(256) void k_step(
    int t, int fused,
    const short* __restrict__ Gin_f, const short* __restrict__ Gin_b,
    const short* __restrict__ X,
    const short* __restrict__ WxT_f, const short* __restrict__ WxT_b,
    const float* __restrict__ bias_f, const float* __restrict__ bias_b,
    const short* __restrict__ WhT_f, const short* __restrict__ WhT_b,
    const short* __restrict__ hin_f, const short* __restrict__ hin_b,
    short* __restrict__ hout_f, short* __restrict__ hout_b,
    float* __restrict__ c_f, float* __restrict__ c_b,
    float* __restrict__ out) {
  int wg = blockIdx.x;
  int dir = wg >> 6;
  int j0 = (wg & 63) * 16;
  int tid = threadIdx.x, lane = tid & 63, g = tid >> 6;
  int lm = lane & 15, lk = (lane >> 4) * 8, lr = lane >> 4;
  int s = dir ? (S_LEN - 1 - t) : t;
  const short* WhT = dir ? WhT_b : WhT_f;
  const short* hin = dir ? hin_b : hin_f;
  short* hout = dir ? hout_b : hout_f;
  float* cbuf = dir ? c_b : c_f;
  int ncol = g * HID + j0 + lm;  // global gate column for this lane's B-fragment

  floatx4 acc[4];
  for (int mt = 0; mt < 4; mt++)
    for (int r = 0; r < 4; r++) acc[mt][r] = 0.f;

  {
    const short* Wrow = WhT + (size_t)ncol * HID;
#pragma unroll 4
    for (int kt = 0; kt < HID; kt += 32) {
      short8 bfrag = *(const short8*)&Wrow[kt + lk];
#pragma unroll
      for (int mt = 0; mt < 4; mt++) {
        short8 afrag = *(const short8*)&hin[(mt * 16 + lm) * HID + kt + lk];
        acc[mt] = __builtin_amdgcn_mfma_f32_16x16x32_bf16(afrag, bfrag, acc[mt], 0, 0, 0);
      }
    }
  }
  if (fused) {  // fallback when ws too small for Gin: recompute x@Wx in-step
    const short* Wrow = (dir ? WxT_b : WxT_f) + (size_t)ncol * HID;
    const short* Xb = X + (size_t)s * BATCH * EMB;
#pragma unroll 4
    for (int kt = 0; kt < EMB; kt += 32) {
      short8 bfrag = *(const short8*)&Wrow[kt + lk];
#pragma unroll
      for (int mt = 0; mt < 4; mt++) {
        short8 afrag = *(const short8*)&Xb[(mt * 16 + lm) * EMB + kt + lk];
        acc[mt] = __builtin_amdgcn_mfma_f32_16x16x32_bf16(afrag, bfrag, acc[mt], 0, 0, 0);
      }
    }
  }

  __shared__ float gl[4][64][16];  // 16 KB: all 4 gates for this WG's tile
  const short* Gin = dir ? Gin_b : Gin_f;
  const float* bias = dir ? bias_b : bias_f;
#pragma unroll
  for (int mt = 0; mt < 4; mt++)
    for (int r = 0; r < 4; r++) {
      int m = mt * 16 + lr * 4 + r;
      float v = acc[mt][r];
      if (fused) v += bias[ncol];
      else       v += bf2f(Gin[(size_t)(s * BATCH + m) * GATES + ncol]);
      gl[g][m][lm] = v;
    }
  __syncthreads();

  for (int p = tid; p < BATCH * 16; p += 256) {
    int m = p >> 4, nl = p & 15;
    int hcol = j0 + nl;
    float iv = gl[0][m][nl], fv = gl[1][m][nl], gv = gl[2][m][nl], ov = gl[3][m][nl];
    float co = cbuf[m * HID + hcol];
    float si = 1.f / (1.f + __expf(-iv));
    float sf = 1.f / (1.f + __expf(-fv));
    float so = 1.f / (1.f + __expf(-ov));
    float cn = sf * co + si * tanhf(gv);
    float hn = so * tanhf(cn);
    cbuf[m * HID + hcol] = cn;
    hout[m * HID + hcol] = f2bf(hn);
    out[(size_t)m * (S_LEN * 2 * HID) + (size_t)s * (2 * HID) + dir * HID + hcol] = hn;
    if (t == S_LEN - 1) {
      size_t hid_base = (size_t)BATCH * S_LEN * 2 * HID;
      out[hid_base + (size_t)m * (2 * HID) + dir * HID + hcol] = hn;
      out[hid_base + (size_t)BATCH * 2 * HID + (size_t)m * (2 * HID) + dir * HID + hcol] = cn;
    }
  }
}

extern "C" void kernel_launch(void* const* d_in, const int* in_sizes, int n_in,
                              void* d_out, int out_size, void* d_ws, size_t ws_size,
                              hipStream_t stream) {
  const int*   tok   = (const int*)d_in[0];
  const float* table = (const float*)d_in[1];
  const float* Wx_f  = (const float*)d_in[2];
  const float* Wh_f  = (const float*)d_in[3];
  const float* b_f   = (const float*)d_in[4];
  const float* Wx_b  = (const float*)d_in[5];
  const float* Wh_b  = (const float*)d_in[6];
  const float* b_b   = (const float*)d_in[7];
  float* out = (float*)d_out;

  char* w = (char*)d_ws;
  short* WxTf = (short*)(w + 0);          // 8 MB each
  short* WxTb = (short*)(w + 8388608);
  short* WhTf = (short*)(w + 16777216);
  short* WhTb = (short*)(w + 25165824);
  char* state = w + 33554432;             // 1 MB state block
  short* h_f1 = (short*)(state);
  short* h_b1 = (short*)(state + 131072);
  float* c_f  = (float*)(state + 262144);
  float* c_b  = (float*)(state + 524288);
  short* h_f2 = (short*)(state + 786432);
  short* h_b2 = (short*)(state + 917504);
  short* X    = (short*)(w + 34603008);   // 64 MB
  short* Ginf = (short*)(w + 101711872);  // 256 MB
  short* Ginb = (short*)(w + 370147328);  // 256 MB
  int fused = (ws_size < 638582784ull) ? 1 : 0;

  k_gather<<<dim3(M_ROWS), dim3(256), 0, stream>>>(tok, table, X);
  k_transpose<<<dim3(32, 128), dim3(256), 0, stream>>>(Wx_f, WxTf);
  k_transpose<<<dim3(32, 128), dim3(256), 0, stream>>>(Wx_b, WxTb);
  k_transpose<<<dim3(32, 128), dim3(256), 0, stream>>>(Wh_f, WhTf);
  k_transpose<<<dim3(32, 128), dim3(256), 0, stream>>>(Wh_b, WhTb);
  k_zero<<<dim3(768), dim3(256), 0, stream>>>((uint32_t*)state, 786432 / 4);
  if (!fused)
    k_gemm_in<<<dim3(32, 256, 2), dim3(256), 0, stream>>>(X, WxTf, WxTb, b_f, b_b, Ginf, Ginb);

  for (int t = 0; t < S_LEN; t++) {
    const short* hinf = (t & 1) ? h_f2 : h_f1;
    const short* hinb = (t & 1) ? h_b2 : h_b1;
    short* houtf = (t & 1) ? h_f1 : h_f2;
    short* houtb = (t & 1) ? h_b1 : h_b2;
    k_step<<<dim3(128), dim3(256), 0, stream>>>(t, fused, Ginf, Ginb, X, WxTf, WxTb, b_f, b_b,
                                                WhTf, WhTb, hinf, hinb, houtf, houtb, c_f, c_b, out);
  }
}